// Round 1
// 704.602 us; speedup vs baseline: 1.0532x; 1.0532x over previous
//
#include <hip/hip_runtime.h>
#include <hip/hip_bf16.h>

// Problem constants
#define NB 8
#define NS 2048
#define ND 768
#define NH 8
#define NHD 96
#define ATTN_SCALE 0.1020620726159658f   // 1/sqrt(96)
#define LOG2E 1.4426950408889634f
#define QSCALE (ATTN_SCALE * LOG2E)      // folded into Q so probs = exp2(s)

#define NX (NB * NS * ND)                // 12,582,912 feature elems
#define NW (ND * ND)                     // 589,824 per weight
#define NMASK64 ((size_t)NB * NS * NS / 64)  // 524,288 ulongs = 4 MB

typedef short sh8 __attribute__((ext_vector_type(8)));   // 8 bf16 = 4 VGPRs (MFMA A/B frag)
typedef float f4  __attribute__((ext_vector_type(4)));   // MFMA C/D frag

__device__ __forceinline__ unsigned int pack_bf2(float a, float b) {
    __hip_bfloat162 h = __float22bfloat162_rn(make_float2(a, b));
    return *reinterpret_cast<unsigned int*>(&h);
}

__device__ __forceinline__ unsigned short f2bf(float a) {
    __hip_bfloat16 h = __float2bfloat16(a);
    return *reinterpret_cast<unsigned short*>(&h);
}

__device__ __forceinline__ void async16(const void* g, void* l) {
    __builtin_amdgcn_global_load_lds(
        (const __attribute__((address_space(1))) unsigned int*)g,
        (__attribute__((address_space(3))) unsigned int*)l, 16, 0, 0);
}

// ---------------------------------------------------------------------------
// Kernel 0: convert X (fp32) and Wq/Wk/Wv (fp32) to bf16.
// Xb/Wb live in d_out (overwritten later by attn -- safe). 8 elems/thread.
// ---------------------------------------------------------------------------
__global__ __launch_bounds__(256) void cvt_bf16(
    const float* __restrict__ X, const float* __restrict__ Wq,
    const float* __restrict__ Wk, const float* __restrict__ Wv,
    __hip_bfloat16* __restrict__ Xb, __hip_bfloat16* __restrict__ Wb)
{
    const long long i8 = ((long long)blockIdx.x * 256 + threadIdx.x) * 8;
    const float* src; __hip_bfloat16* dst; long long off;
    if (i8 < NX) { src = X; dst = Xb; off = i8; }
    else {
        const long long j = i8 - NX;
        const int w = (int)(j / NW);
        off = j - (long long)w * NW;
        src = (w == 0) ? Wq : (w == 1) ? Wk : Wv;
        dst = Wb + (long long)w * NW;
    }
    const float4 a = *(const float4*)&src[off];
    const float4 b = *(const float4*)&src[off + 4];
    const uint4 o = make_uint4(pack_bf2(a.x, a.y), pack_bf2(a.z, a.w),
                               pack_bf2(b.x, b.y), pack_bf2(b.z, b.w));
    *(uint4*)&dst[off] = o;
}

// ---------------------------------------------------------------------------
// Kernel 0b: bit-pack adj (int32 0/1, 128 MB) into 64-bit column masks (4 MB).
// One wave produces one ulong per iteration via __ballot; 8192 waves,
// grid-stride over 524288 ulongs (64 iters each). Reads coalesced 256B/wave.
// ---------------------------------------------------------------------------
__global__ __launch_bounds__(256) void adj_mask(
    const int* __restrict__ adj, unsigned long long* __restrict__ mask)
{
    const int wid  = (blockIdx.x << 2) + (threadIdx.x >> 6);
    const int lane = threadIdx.x & 63;
    const int nwaves = 2048 * 4;
    for (size_t u = wid; u < NMASK64; u += nwaves) {
        const int v = adj[u * 64 + lane];
        const unsigned long long m = __ballot(v != 0);
        if (lane == 0) mask[u] = m;
    }
}

// ---------------------------------------------------------------------------
// Kernel 1: QKV projection, m97-style: 128x128 tile, BK=64, global_load_lds
// width-16 staging, bf16 MFMA. 256 threads = 4 waves in 2x2.
// z: 0=Q (scaled by QSCALE, [B,H,S,HD]), 1=K ([B,H,S,HD]), 2=V^T ([B,H,HD,S]).
// ---------------------------------------------------------------------------
__global__ __launch_bounds__(256) void qkv_mfma(
    const __hip_bfloat16* __restrict__ Xb, const __hip_bfloat16* __restrict__ Wb,
    const float* __restrict__ bq, const float* __restrict__ bk,
    const float* __restrict__ bv,
    __hip_bfloat16* __restrict__ Qo, __hip_bfloat16* __restrict__ Ko,
    __hip_bfloat16* __restrict__ Vo)
{
    __shared__ unsigned short As[128 * 64];  // X tile [m][k] flat (async dest)
    __shared__ unsigned short Bs[128 * 64];  // W tile [n][k] flat

    const int z = blockIdx.z;
    const __hip_bfloat16* W = Wb + (size_t)z * NW;
    const float* bias = (z == 0) ? bq : (z == 1) ? bk : bv;

    const int tid  = threadIdx.x;
    const int w    = tid >> 6;
    const int lane = tid & 63;
    const int quad = lane >> 4;
    const int nl   = lane & 15;
    const int wm = w >> 1, wn = w & 1;
    const int m0 = blockIdx.y << 7;
    const int n0 = blockIdx.x << 7;

    const bool swapped = (z != 2);

    const f4 zero4 = {0.f, 0.f, 0.f, 0.f};
    f4 acc[4][4];
    #pragma unroll
    for (int i = 0; i < 4; ++i)
        #pragma unroll
        for (int j = 0; j < 4; ++j) acc[i][j] = zero4;

    for (int k0 = 0; k0 < ND; k0 += 64) {
        #pragma unroll
        for (int i = 0; i < 4; ++i) {
            const int cb = (i << 8) + (w << 6);      // wave-uniform chunk base
            const int c  = cb + lane;
            const int row = c >> 3, col = (c & 7) << 3;
            async16(&Xb[(size_t)(m0 + row) * ND + k0 + col], &As[(size_t)cb << 3]);
            async16(&W [(size_t)(n0 + row) * ND + k0 + col], &Bs[(size_t)cb << 3]);
        }
        __syncthreads();   // drains vmcnt -> staging visible

        const unsigned short* Arow = swapped ? Bs : As;
        const unsigned short* Brow = swapped ? As : Bs;
        sh8 af[4][2], bfr[4][2];
        #pragma unroll
        for (int t = 0; t < 4; ++t)
            #pragma unroll
            for (int kc = 0; kc < 2; ++kc) {
                af[t][kc]  = *(const sh8*)&Arow[((wm << 6) + (t << 4) + nl) * 64 + (kc << 5) + (quad << 3)];
                bfr[t][kc] = *(const sh8*)&Brow[((wn << 6) + (t << 4) + nl) * 64 + (kc << 5) + (quad << 3)];
            }
        #pragma unroll
        for (int mt = 0; mt < 4; ++mt)
            #pragma unroll
            for (int nt = 0; nt < 4; ++nt)
                #pragma unroll
                for (int kc = 0; kc < 2; ++kc)
                    acc[mt][nt] = __builtin_amdgcn_mfma_f32_16x16x32_bf16(
                        af[mt][kc], bfr[nt][kc], acc[mt][nt], 0, 0, 0);
        __syncthreads();
    }

    if (swapped) {
        __hip_bfloat16* Out = (z == 0) ? Qo : Ko;
        const float sc = (z == 0) ? QSCALE : 1.0f;
        #pragma unroll
        for (int mt = 0; mt < 4; ++mt) {
            const int nb = n0 + (wm << 6) + (mt << 4) + (quad << 2);  // 4-aligned
            const int hh = nb / NHD, hd0 = nb % NHD;
            const float4 bn = *(const float4*)&bias[nb];
            #pragma unroll
            for (int nt = 0; nt < 4; ++nt) {
                const int m = m0 + (wn << 6) + (nt << 4) + nl;
                const int bb = m >> 11;
                const int s  = m & (NS - 1);
                const f4 a = acc[mt][nt];
                const uint2 pk = make_uint2(
                    pack_bf2((a[0] + bn.x) * sc, (a[1] + bn.y) * sc),
                    pack_bf2((a[2] + bn.z) * sc, (a[3] + bn.w) * sc));
                *(uint2*)&Out[((size_t)(bb * NH + hh) * NS + s) * NHD + hd0] = pk;
            }
        }
    } else {
        #pragma unroll
        for (int mt = 0; mt < 4; ++mt) {
            const int mb = m0 + (wm << 6) + (mt << 4) + (quad << 2);
            const int bb = mb >> 11;
            const int s0 = mb & (NS - 1);
            #pragma unroll
            for (int nt = 0; nt < 4; ++nt) {
                const int n = n0 + (wn << 6) + (nt << 4) + nl;
                const int hh = n / NHD, hd = n % NHD;
                const float bn = bias[n];
                const f4 a = acc[mt][nt];
                const uint2 pk = make_uint2(pack_bf2(a[0] + bn, a[1] + bn),
                                            pack_bf2(a[2] + bn, a[3] + bn));
                *(uint2*)&Vo[((size_t)(bb * NH + hh) * NHD + hd) * NS + s0] = pk;
            }
        }
    }
}

// ---------------------------------------------------------------------------
// Kernel 2: MFMA flash attention + residual.
// Changes vs previous round (counter-driven):
//  (1) amdgpu_waves_per_eu(2,3): the allocator was squeezing to 76 VGPR and
//      spilling (~380 MB/dispatch of scratch write-back = the WRITE_SIZE
//      anomaly). Occupancy is LDS-capped at 3 blocks/CU (=3 waves/EU), so
//      max=3 removes any incentive to squeeze; min=2 gives a 256-reg budget.
//  (2) K tile XOR-swizzle, both-sides (G21): Ks rows are 192 B (16 words mod
//      32) -> ds_read_b128 at [ct*16+nl][...] was an 8-way bank conflict.
//      LDS dest stays linear (async16 requirement); the per-lane GLOBAL
//      source chunk is pre-swizzled (c' = row*12 + (cc ^ ((row>>1)&3))) and
//      reads XOR the elem offset with ((nl>>1)&3)<<3 -> 8 distinct bank
//      starts per 16-lane group = 2-way = free.
//  (3) USEM path: adj pre-packed to 64-bit masks (4 MB, L2-resident) ->
//      4 broadcast 8B loads/iter instead of 16 scalar dword loads, and 8
//      fewer live regs. Guarded by ws_size; USEM=0 keeps the old adj path.
// ---------------------------------------------------------------------------
template<int USEM>
__global__ __launch_bounds__(256)
__attribute__((amdgpu_waves_per_eu(2, 3)))
void attn_mfma(
    const __hip_bfloat16* __restrict__ Qg, const __hip_bfloat16* __restrict__ Kg,
    const __hip_bfloat16* __restrict__ Vtg, const int* __restrict__ adj,
    const unsigned long long* __restrict__ amask,
    const float* __restrict__ features, float* __restrict__ out)
{
    __shared__ unsigned short Ks[2][64][96];  // unpadded async16 image, dbuf, SWIZZLED
    __shared__ unsigned short Vs[96][72];     // [d][kv], padded (144B rows)
    __shared__ unsigned short Pb[64][72];     // P bf16, padded (144B rows)

    const int tid  = threadIdx.x;
    const int w    = tid >> 6;
    const int lane = tid & 63;
    const int quad = lane >> 4;
    const int nl   = lane & 15;
    const int qt = blockIdx.x, h = blockIdx.y, b = blockIdx.z;
    const int sq0 = qt << 6;

    const size_t bh = (size_t)b * NH + h;
    const __hip_bfloat16* Qbase = Qg + (bh * NS + sq0) * NHD;
    const __hip_bfloat16* Kbase = Kg + bh * NS * NHD;   // [s][hd], tile-linear
    const __hip_bfloat16* Vbase = Vtg + bh * NHD * NS;  // V^T: [hd][s]
    const int* adjbase = adj + ((size_t)b * NS + sq0) * NS;
    const unsigned long long* mbase = amask + ((size_t)b * NS + sq0) * (NS / 64);

    // V staging coords (loop-invariant): 768 chunks = 96 rows x 8
    int vrow[3], vc8[3];
    #pragma unroll
    for (int i = 0; i < 3; ++i) {
        const int f = tid + (i << 8);
        vrow[i] = f >> 3; vc8[i] = f & 7;
    }

    // K source-chunk swizzle (loop-invariant): phys chunk c (12 chunks/row)
    // must hold logical chunk row*12 + (cc ^ ((row>>1)&3)).
    int ksrc[3];
    #pragma unroll
    for (int i = 0; i < 3; ++i) {
        const int c  = (i << 8) + tid;        // == cb + lane
        const int kr = c / 12, kcc = c - kr * 12;
        ksrc[i] = kr * 12 + (kcc ^ ((kr >> 1) & 3));
    }
    // Read-side XOR in ushort units (bits 3..4): row=ct*16+nl -> depends on nl only
    const int kswz = ((nl >> 1) & 3) << 3;

    // Q fragments (A-operand), pre-scaled by QSCALE at projection
    sh8 qf[3];
    #pragma unroll
    for (int kc = 0; kc < 3; ++kc)
        qf[kc] = *(const sh8*)&Qbase[(size_t)((w << 4) + nl) * NHD + kc * 32 + (quad << 3)];

    const f4 zero4 = {0.f, 0.f, 0.f, 0.f};
    f4 o[6];
    float l_acc[4];
    #pragma unroll
    for (int t = 0; t < 6; ++t) o[t] = zero4;
    #pragma unroll
    for (int r = 0; r < 4; ++r) l_acc[r] = 0.f;

    // Preloop: async K(0) -> Ks[0] (swizzled source); sync-preload V(0) into regs.
    #pragma unroll
    for (int i = 0; i < 3; ++i) {
        const int cb = (i << 8) + (w << 6);   // wave-uniform chunk base
        async16(&Kbase[(size_t)ksrc[i] << 3], &Ks[0][0][(size_t)cb << 3]);
    }
    uint4 vr[3];
    #pragma unroll
    for (int i = 0; i < 3; ++i)
        vr[i] = *(const uint4*)&Vbase[(size_t)vrow[i] * NS + (vc8[i] << 3)];

    for (int kt = 0; kt < 32; ++kt) {
        const int sk0 = kt << 6;
        const int buf = kt & 1;

        // Commit prefetched V regs to LDS
        #pragma unroll
        for (int i = 0; i < 3; ++i)
            *(uint4*)&Vs[vrow[i]][vc8[i] << 3] = vr[i];
        __syncthreads();   // (a) V staging + prior K async visible

        // Mask/adj for THIS tile -- issued first (oldest) so consuming it
        // below waits vmcnt(<=N), leaving the V/K prefetch in flight.
        unsigned long long mrow[4];
        int am[4][4];
        if constexpr (USEM) {
            #pragma unroll
            for (int r = 0; r < 4; ++r)
                mrow[r] = mbase[(size_t)((w << 4) + (quad << 2) + r) * (NS / 64) + kt];
        } else {
            #pragma unroll
            for (int ct = 0; ct < 4; ++ct)
                #pragma unroll
                for (int r = 0; r < 4; ++r)
                    am[ct][r] = adjbase[(size_t)((w << 4) + (quad << 2) + r) * NS +
                                        sk0 + (ct << 4) + nl];
        }

        if (kt < 31) {
            const int skn = sk0 + 64;
            // V(kt+1) -> regs
            #pragma unroll
            for (int i = 0; i < 3; ++i)
                vr[i] = *(const uint4*)&Vbase[(size_t)vrow[i] * NS + skn + (vc8[i] << 3)];
            // K(kt+1) -> other LDS buffer (swizzled source), zero registers
            #pragma unroll
            for (int i = 0; i < 3; ++i) {
                const int cb = (i << 8) + (w << 6);
                async16(&Kbase[((size_t)skn * 12 + ksrc[i]) << 3],
                        &Ks[buf ^ 1][0][(size_t)cb << 3]);
            }
        }

        // Scores: 16 q x 64 kv per wave (swizzled K reads: 2-way, free)
        f4 sc[4];
        #pragma unroll
        for (int ct = 0; ct < 4; ++ct) sc[ct] = zero4;
        #pragma unroll
        for (int ct = 0; ct < 4; ++ct)
            #pragma unroll
            for (int kc = 0; kc < 3; ++kc) {
                const sh8 kf = *(const sh8*)&Ks[buf][(ct << 4) + nl]
                                               [(kc * 32 + (quad << 3)) ^ kswz];
                sc[ct] = __builtin_amdgcn_mfma_f32_16x16x32_bf16(qf[kc], kf, sc[ct], 0, 0, 0);
            }

        // No-max softmax: p = adj ? 2^s : 0  (s pre-scaled by log2e/sqrt(hd))
        float pr[4][4];
        #pragma unroll
        for (int ct = 0; ct < 4; ++ct)
            #pragma unroll
            for (int r = 0; r < 4; ++r) {
                bool keep;
                if constexpr (USEM)
                    keep = (mrow[r] >> ((ct << 4) + nl)) & 1ULL;
                else
                    keep = (am[ct][r] != 0);
                pr[ct][r] = keep ? __builtin_amdgcn_exp2f(sc[ct][r]) : 0.f;
            }
        #pragma unroll
        for (int r = 0; r < 4; ++r)
            l_acc[r] += (pr[0][r] + pr[1][r]) + (pr[2][r] + pr[3][r]);

        // Write P as bf16 (wave-private rows; b16 writes are 2-way = free)
        const int rowbase = (w << 4) + (quad << 2);
        #pragma unroll
        for (int ct = 0; ct < 4; ++ct)
            #pragma unroll
            for (int r = 0; r < 4; ++r)
                Pb[rowbase + r][(ct << 4) + nl] = f2bf(pr[ct][r]);
        // No barrier: wave w reads back only its own rows (lgkmcnt-ordered)

        sh8 pf[2];
        #pragma unroll
        for (int kc2 = 0; kc2 < 2; ++kc2)
            pf[kc2] = *(const sh8*)&Pb[(w << 4) + nl][(kc2 << 5) + (quad << 3)];

        // PV: O[16 q][96 hd] += P[16][64] @ V[64][96]
        #pragma unroll
        for (int t = 0; t < 6; ++t)
            #pragma unroll
            for (int kc2 = 0; kc2 < 2; ++kc2) {
                const sh8 vf = *(const sh8*)&Vs[(t << 4) + nl][(kc2 << 5) + (quad << 3)];
                o[t] = __builtin_amdgcn_mfma_f32_16x16x32_bf16(pf[kc2], vf, o[t], 0, 0, 0);
            }
        __syncthreads();   // (b) all reads done; drains K/V prefetch (full-iter overlap)
    }

    // Deferred l reduction (over the 16 nl lanes of each row)
    float inv[4];
    #pragma unroll
    for (int r = 0; r < 4; ++r) {
        float l = l_acc[r];
        l += __shfl_xor(l, 1);
        l += __shfl_xor(l, 2);
        l += __shfl_xor(l, 4);
        l += __shfl_xor(l, 8);
        inv[r] = 1.0f / l;
    }

    // Epilogue: O/l + residual
    #pragma unroll
    for (int r = 0; r < 4; ++r) {
        const int srow = sq0 + (w << 4) + (quad << 2) + r;
        const size_t base = ((size_t)b * NS + srow) * ND + h * NHD;
        #pragma unroll
        for (int t = 0; t < 6; ++t) {
            const int d = (t << 4) + nl;
            out[base + d] = o[t][r] * inv[r] + features[base + d];
        }
    }
}

// ---------------------------------------------------------------------------
// Kernel 3: in-place LayerNorm over last dim (768). One wave per row.
// ---------------------------------------------------------------------------
__global__ __launch_bounds__(256) void ln_kernel(
    float* __restrict__ out, const float* __restrict__ gamma,
    const float* __restrict__ beta)
{
    const int row = (blockIdx.x << 2) + (threadIdx.x >> 6);
    const int lane = threadIdx.x & 63;
    float* p = out + (size_t)row * ND;

    float4 v[3];
    float s = 0.f, sq = 0.f;
    #pragma unroll
    for (int i = 0; i < 3; ++i) {
        v[i] = *(const float4*)&p[(i << 8) + (lane << 2)];
        s += v[i].x + v[i].y + v[i].z + v[i].w;
        sq += v[i].x * v[i].x + v[i].y * v[i].y + v[i].z * v[i].z + v[i].w * v[i].w;
    }
    #pragma unroll
    for (int off = 32; off; off >>= 1) {
        s += __shfl_xor(s, off);
        sq += __shfl_xor(sq, off);
    }
    const float mu = s * (1.0f / ND);
    const float var = sq * (1.0f / ND) - mu * mu;
    const float rs = rsqrtf(var + 1e-5f);
    #pragma unroll
    for (int i = 0; i < 3; ++i) {
        const int d = (i << 8) + (lane << 2);
        const float4 g = *(const float4*)&gamma[d];
        const float4 be = *(const float4*)&beta[d];
        float4 ov;
        ov.x = (v[i].x - mu) * rs * g.x + be.x;
        ov.y = (v[i].y - mu) * rs * g.y + be.y;
        ov.z = (v[i].z - mu) * rs * g.z + be.z;
        ov.w = (v[i].w - mu) * rs * g.w + be.w;
        *(float4*)&p[d] = ov;
    }
}

// ---------------------------------------------------------------------------
extern "C" void kernel_launch(void* const* d_in, const int* in_sizes, int n_in,
                              void* d_out, int out_size, void* d_ws, size_t ws_size,
                              hipStream_t stream) {
    (void)in_sizes; (void)n_in; (void)out_size;

    const float* features = (const float*)d_in[0];
    const int*   adj      = (const int*)d_in[1];
    const float* Wq       = (const float*)d_in[2];
    const float* bq       = (const float*)d_in[3];
    const float* Wk       = (const float*)d_in[4];
    const float* bk       = (const float*)d_in[5];
    const float* Wv       = (const float*)d_in[6];
    const float* bv       = (const float*)d_in[7];
    const float* gamma    = (const float*)d_in[8];
    const float* beta     = (const float*)d_in[9];
    float* out = (float*)d_out;

    // bf16 X and W live in d_out (fully overwritten later by attn+ln).
    __hip_bfloat16* Xb = (__hip_bfloat16*)d_out;
    __hip_bfloat16* Wb = Xb + (size_t)NX;
    // Q/K/V bf16 in workspace (V stored transposed [B,H,HD,S]).
    __hip_bfloat16* Qb = (__hip_bfloat16*)d_ws;
    __hip_bfloat16* Kb = Qb + (size_t)NX;
    __hip_bfloat16* Vb = Kb + (size_t)NX;
    // Packed adj mask after Vb -- only if the workspace is big enough.
    unsigned long long* Mask = (unsigned long long*)(Vb + (size_t)NX);
    const size_t ws_need = (size_t)NX * 2 * 3 + NMASK64 * 8;
    const bool use_mask = (ws_size >= ws_need);

    // 0) fp32 -> bf16 convert (X + 3 weights)
    cvt_bf16<<<(NX + 3 * NW) / (8 * 256), 256, 0, stream>>>(
        features, Wq, Wk, Wv, Xb, Wb);

    // 0b) adj -> bitmask (128 MB -> 4 MB), only when ws has room
    if (use_mask)
        adj_mask<<<2048, 256, 0, stream>>>(adj, Mask);

    // 1) QKV projections: grid (N/128, M/128, 3)
    dim3 g1(ND / 128, (NB * NS) / 128, 3);
    qkv_mfma<<<g1, 256, 0, stream>>>(Xb, Wb, bq, bk, bv, Qb, Kb, Vb);

    // 2) MFMA flash attention + residual: grid (S/64, H, B)
    dim3 g2(NS / 64, NH, NB);
    if (use_mask)
        attn_mfma<1><<<g2, 256, 0, stream>>>(Qb, Kb, Vb, adj, Mask, features, out);
    else
        attn_mfma<0><<<g2, 256, 0, stream>>>(Qb, Kb, Vb, adj, Mask, features, out);

    // 3) LayerNorm in place
    ln_kernel<<<(NB * NS) / 4, 256, 0, stream>>>(out, gamma, beta);
}

// Round 2
// 668.895 us; speedup vs baseline: 1.1094x; 1.0534x over previous
//
#include <hip/hip_runtime.h>
#include <hip/hip_bf16.h>

// Problem constants
#define NB 8
#define NS 2048
#define ND 768
#define NH 8
#define NHD 96
#define ATTN_SCALE 0.1020620726159658f   // 1/sqrt(96)
#define LOG2E 1.4426950408889634f
#define QSCALE (ATTN_SCALE * LOG2E)      // folded into Q so probs = exp2(s)

#define NX (NB * NS * ND)                // 12,582,912 feature elems
#define NW (ND * ND)                     // 589,824 per weight
#define NMASK64 ((size_t)NB * NS * NS / 64)  // 524,288 ulongs = 4 MB

typedef short sh8 __attribute__((ext_vector_type(8)));   // 8 bf16 = 4 VGPRs (MFMA A/B frag)
typedef float f4  __attribute__((ext_vector_type(4)));   // MFMA C/D frag

__device__ __forceinline__ unsigned int pack_bf2(float a, float b) {
    __hip_bfloat162 h = __float22bfloat162_rn(make_float2(a, b));
    return *reinterpret_cast<unsigned int*>(&h);
}

__device__ __forceinline__ void async16(const void* g, void* l) {
    __builtin_amdgcn_global_load_lds(
        (const __attribute__((address_space(1))) unsigned int*)g,
        (__attribute__((address_space(3))) unsigned int*)l, 16, 0, 0);
}

// ---------------------------------------------------------------------------
// Kernel 0: convert X (fp32) and Wq/Wk/Wv (fp32) to bf16.
// ---------------------------------------------------------------------------
__global__ __launch_bounds__(256) void cvt_bf16(
    const float* __restrict__ X, const float* __restrict__ Wq,
    const float* __restrict__ Wk, const float* __restrict__ Wv,
    __hip_bfloat16* __restrict__ Xb, __hip_bfloat16* __restrict__ Wb)
{
    const long long i8 = ((long long)blockIdx.x * 256 + threadIdx.x) * 8;
    const float* src; __hip_bfloat16* dst; long long off;
    if (i8 < NX) { src = X; dst = Xb; off = i8; }
    else {
        const long long j = i8 - NX;
        const int w = (int)(j / NW);
        off = j - (long long)w * NW;
        src = (w == 0) ? Wq : (w == 1) ? Wk : Wv;
        dst = Wb + (long long)w * NW;
    }
    const float4 a = *(const float4*)&src[off];
    const float4 b = *(const float4*)&src[off + 4];
    const uint4 o = make_uint4(pack_bf2(a.x, a.y), pack_bf2(a.z, a.w),
                               pack_bf2(b.x, b.y), pack_bf2(b.z, b.w));
    *(uint4*)&dst[off] = o;
}

// ---------------------------------------------------------------------------
// Kernel 0b: bit-pack adj (int32 0/1, 128 MB) into 64-bit column masks (4 MB).
// ---------------------------------------------------------------------------
__global__ __launch_bounds__(256) void adj_mask(
    const int* __restrict__ adj, unsigned long long* __restrict__ mask)
{
    const int wid  = (blockIdx.x << 2) + (threadIdx.x >> 6);
    const int lane = threadIdx.x & 63;
    const int nwaves = 2048 * 4;
    for (size_t u = wid; u < NMASK64; u += nwaves) {
        const int v = adj[u * 64 + lane];
        const unsigned long long m = __ballot(v != 0);
        if (lane == 0) mask[u] = m;
    }
}

// ---------------------------------------------------------------------------
// Kernel 1: QKV projection (m97-style 128x128 tile, BK=64, async staging).
// ---------------------------------------------------------------------------
__global__ __launch_bounds__(256) void qkv_mfma(
    const __hip_bfloat16* __restrict__ Xb, const __hip_bfloat16* __restrict__ Wb,
    const float* __restrict__ bq, const float* __restrict__ bk,
    const float* __restrict__ bv,
    __hip_bfloat16* __restrict__ Qo, __hip_bfloat16* __restrict__ Ko,
    __hip_bfloat16* __restrict__ Vo)
{
    __shared__ unsigned short As[128 * 64];  // X tile [m][k] flat (async dest)
    __shared__ unsigned short Bs[128 * 64];  // W tile [n][k] flat

    const int z = blockIdx.z;
    const __hip_bfloat16* W = Wb + (size_t)z * NW;
    const float* bias = (z == 0) ? bq : (z == 1) ? bk : bv;

    const int tid  = threadIdx.x;
    const int w    = tid >> 6;
    const int lane = tid & 63;
    const int quad = lane >> 4;
    const int nl   = lane & 15;
    const int wm = w >> 1, wn = w & 1;
    const int m0 = blockIdx.y << 7;
    const int n0 = blockIdx.x << 7;

    const bool swapped = (z != 2);

    const f4 zero4 = {0.f, 0.f, 0.f, 0.f};
    f4 acc[4][4];
    #pragma unroll
    for (int i = 0; i < 4; ++i)
        #pragma unroll
        for (int j = 0; j < 4; ++j) acc[i][j] = zero4;

    for (int k0 = 0; k0 < ND; k0 += 64) {
        #pragma unroll
        for (int i = 0; i < 4; ++i) {
            const int cb = (i << 8) + (w << 6);      // wave-uniform chunk base
            const int c  = cb + lane;
            const int row = c >> 3, col = (c & 7) << 3;
            async16(&Xb[(size_t)(m0 + row) * ND + k0 + col], &As[(size_t)cb << 3]);
            async16(&W [(size_t)(n0 + row) * ND + k0 + col], &Bs[(size_t)cb << 3]);
        }
        __syncthreads();   // drains vmcnt -> staging visible

        const unsigned short* Arow = swapped ? Bs : As;
        const unsigned short* Brow = swapped ? As : Bs;
        sh8 af[4][2], bfr[4][2];
        #pragma unroll
        for (int t = 0; t < 4; ++t)
            #pragma unroll
            for (int kc = 0; kc < 2; ++kc) {
                af[t][kc]  = *(const sh8*)&Arow[((wm << 6) + (t << 4) + nl) * 64 + (kc << 5) + (quad << 3)];
                bfr[t][kc] = *(const sh8*)&Brow[((wn << 6) + (t << 4) + nl) * 64 + (kc << 5) + (quad << 3)];
            }
        #pragma unroll
        for (int mt = 0; mt < 4; ++mt)
            #pragma unroll
            for (int nt = 0; nt < 4; ++nt)
                #pragma unroll
                for (int kc = 0; kc < 2; ++kc)
                    acc[mt][nt] = __builtin_amdgcn_mfma_f32_16x16x32_bf16(
                        af[mt][kc], bfr[nt][kc], acc[mt][nt], 0, 0, 0);
        __syncthreads();
    }

    if (swapped) {
        __hip_bfloat16* Out = (z == 0) ? Qo : Ko;
        const float sc = (z == 0) ? QSCALE : 1.0f;
        #pragma unroll
        for (int mt = 0; mt < 4; ++mt) {
            const int nb = n0 + (wm << 6) + (mt << 4) + (quad << 2);  // 4-aligned
            const int hh = nb / NHD, hd0 = nb % NHD;
            const float4 bn = *(const float4*)&bias[nb];
            #pragma unroll
            for (int nt = 0; nt < 4; ++nt) {
                const int m = m0 + (wn << 6) + (nt << 4) + nl;
                const int bb = m >> 11;
                const int s  = m & (NS - 1);
                const f4 a = acc[mt][nt];
                const uint2 pk = make_uint2(
                    pack_bf2((a[0] + bn.x) * sc, (a[1] + bn.y) * sc),
                    pack_bf2((a[2] + bn.z) * sc, (a[3] + bn.w) * sc));
                *(uint2*)&Out[((size_t)(bb * NH + hh) * NS + s) * NHD + hd0] = pk;
            }
        }
    } else {
        #pragma unroll
        for (int mt = 0; mt < 4; ++mt) {
            const int mb = m0 + (wm << 6) + (mt << 4) + (quad << 2);
            const int bb = mb >> 11;
            const int s0 = mb & (NS - 1);
            #pragma unroll
            for (int nt = 0; nt < 4; ++nt) {
                const int n = n0 + (wn << 6) + (nt << 4) + nl;
                const int hh = n / NHD, hd = n % NHD;
                const float bn = bias[n];
                const f4 a = acc[mt][nt];
                const uint2 pk = make_uint2(pack_bf2(a[0] + bn, a[1] + bn),
                                            pack_bf2(a[2] + bn, a[3] + bn));
                *(uint2*)&Vo[((size_t)(bb * NH + hh) * NHD + hd) * NS + s0] = pk;
            }
        }
    }
}

// ---------------------------------------------------------------------------
// Kernel 2: MFMA flash attention + residual.
// Round-2 changes (counter-driven):
//  (1) XCD-aware block remap: flat -> wid = (flat&7)*256 + flat/8, so XCD k
//      owns batch b=k with qt fastest. Resident blocks per XCD then span ~3
//      (b,h) groups = 2.4 MB of K/V -> L2-resident instead of streaming from
//      Infinity Cache every iteration (the per-iter vmcnt(0) barrier drain
//      was eating ~4 us/iter of L3 queueing latency).
//  (2) Swapped QK^T: sc = mfma(K, Q) -> C[kv][q]; each lane owns one q-row.
//      Mask = ONE u64 load/iter (pipelined one iter ahead) instead of 4;
//      l = 1 scalar + 2 shuffles; P written as 8 packed b32 instead of
//      16 b16. ~20 fewer peak-live VGPRs, 3 fewer global loads/iter.
//  (3) K source-chunk swizzle retained (r1: conflicts 2.7e7 -> 1.47e7).
// ---------------------------------------------------------------------------
template<int USEM>
__global__ __launch_bounds__(256)
__attribute__((amdgpu_waves_per_eu(2, 3)))
void attn_mfma(
    const __hip_bfloat16* __restrict__ Qg, const __hip_bfloat16* __restrict__ Kg,
    const __hip_bfloat16* __restrict__ Vtg, const int* __restrict__ adj,
    const unsigned long long* __restrict__ amask,
    const float* __restrict__ features, float* __restrict__ out)
{
    __shared__ unsigned short Ks[2][64][96];  // unpadded async16 image, dbuf, swizzled
    __shared__ unsigned short Vs[96][72];     // [d][kv], padded (144B rows)
    __shared__ unsigned short Pb[64][72];     // P bf16, padded (144B rows)

    const int tid  = threadIdx.x;
    const int w    = tid >> 6;
    const int lane = tid & 63;
    const int quad = lane >> 4;
    const int nl   = lane & 15;

    // XCD-aware remap: hardware round-robins flat id over 8 XCDs; wid makes
    // XCD k = batch k, qt fastest (2048 % 8 == 0 -> simple form bijective).
    const int flat = blockIdx.x + (blockIdx.y << 5) + (blockIdx.z << 8);
    const int wid  = ((flat & 7) << 8) + (flat >> 3);
    const int qt = wid & 31, h = (wid >> 5) & 7, b = wid >> 8;
    const int sq0 = qt << 6;

    const size_t bh = (size_t)b * NH + h;
    const __hip_bfloat16* Qbase = Qg + (bh * NS + sq0) * NHD;
    const __hip_bfloat16* Kbase = Kg + bh * NS * NHD;   // [s][hd], tile-linear
    const __hip_bfloat16* Vbase = Vtg + bh * NHD * NS;  // V^T: [hd][s]
    const int* adjbase = adj + ((size_t)b * NS + sq0) * NS;
    // This lane's q-row (swapped layout): q = w*16 + nl
    const unsigned long long* mrowp =
        amask + ((size_t)b * NS + sq0 + (w << 4) + nl) * (NS / 64);

    // V staging coords (loop-invariant): 768 chunks = 96 rows x 8
    int vrow[3], vc8[3];
    #pragma unroll
    for (int i = 0; i < 3; ++i) {
        const int f = tid + (i << 8);
        vrow[i] = f >> 3; vc8[i] = f & 7;
    }

    // K source-chunk swizzle (loop-invariant)
    int ksrc[3];
    #pragma unroll
    for (int i = 0; i < 3; ++i) {
        const int c  = (i << 8) + tid;
        const int kr = c / 12, kcc = c - kr * 12;
        ksrc[i] = kr * 12 + (kcc ^ ((kr >> 1) & 3));
    }
    const int kswz = ((nl >> 1) & 3) << 3;   // read-side XOR, ushort units

    // Q fragments (B-operand now), pre-scaled by QSCALE at projection
    sh8 qf[3];
    #pragma unroll
    for (int kc = 0; kc < 3; ++kc)
        qf[kc] = *(const sh8*)&Qbase[(size_t)((w << 4) + nl) * NHD + kc * 32 + (quad << 3)];

    const f4 zero4 = {0.f, 0.f, 0.f, 0.f};
    f4 o[6];
    #pragma unroll
    for (int t = 0; t < 6; ++t) o[t] = zero4;
    float l_acc = 0.f;

    // Preloop: async K(0) -> Ks[0]; V(0) -> regs; mask(0) -> reg.
    #pragma unroll
    for (int i = 0; i < 3; ++i) {
        const int cb = (i << 8) + (w << 6);
        async16(&Kbase[(size_t)ksrc[i] << 3], &Ks[0][0][(size_t)cb << 3]);
    }
    uint4 vr[3];
    #pragma unroll
    for (int i = 0; i < 3; ++i)
        vr[i] = *(const uint4*)&Vbase[(size_t)vrow[i] * NS + (vc8[i] << 3)];
    unsigned long long mcur = 0;
    if constexpr (USEM) mcur = mrowp[0];

    for (int kt = 0; kt < 32; ++kt) {
        const int sk0 = kt << 6;
        const int buf = kt & 1;

        // Commit prefetched V regs to LDS
        #pragma unroll
        for (int i = 0; i < 3; ++i)
            *(uint4*)&Vs[vrow[i]][vc8[i] << 3] = vr[i];
        __syncthreads();   // (a) V staging + prior K async visible

        unsigned long long mrow;
        if constexpr (USEM) {
            mrow = mcur;                       // pipelined one iter ahead
        } else {
            mrow = 0;
            #pragma unroll
            for (int ct = 0; ct < 4; ++ct)
                #pragma unroll
                for (int r = 0; r < 4; ++r) {
                    const int kb = (ct << 4) + (quad << 2) + r;
                    const int v = adjbase[(size_t)((w << 4) + nl) * NS + sk0 + kb];
                    mrow |= (unsigned long long)(v != 0) << kb;
                }
        }

        if (kt < 31) {
            const int skn = sk0 + 64;
            // V(kt+1) -> regs
            #pragma unroll
            for (int i = 0; i < 3; ++i)
                vr[i] = *(const uint4*)&Vbase[(size_t)vrow[i] * NS + skn + (vc8[i] << 3)];
            // K(kt+1) -> other LDS buffer, zero registers
            #pragma unroll
            for (int i = 0; i < 3; ++i) {
                const int cb = (i << 8) + (w << 6);
                async16(&Kbase[((size_t)skn * 12 + ksrc[i]) << 3],
                        &Ks[buf ^ 1][0][(size_t)cb << 3]);
            }
            if constexpr (USEM) mcur = mrowp[kt + 1];   // mask(kt+1)
        }

        // Scores, SWAPPED: sc[ct] = K_tile(ct) x Q -> C[kv][q].
        // Lane (quad,nl): q = w*16+nl, kv = 16ct + 4quad + r.
        f4 sc[4];
        #pragma unroll
        for (int ct = 0; ct < 4; ++ct) sc[ct] = zero4;
        #pragma unroll
        for (int ct = 0; ct < 4; ++ct)
            #pragma unroll
            for (int kc = 0; kc < 3; ++kc) {
                const sh8 kf = *(const sh8*)&Ks[buf][(ct << 4) + nl]
                                               [(kc * 32 + (quad << 3)) ^ kswz];
                sc[ct] = __builtin_amdgcn_mfma_f32_16x16x32_bf16(kf, qf[kc], sc[ct], 0, 0, 0);
            }

        // Softmax numerators, streamed per ct: p = maskbit ? 2^s : 0.
        // Write P pairs as packed b32 into Pb[q][kv].
        const int prow = (w << 4) + nl;
        #pragma unroll
        for (int ct = 0; ct < 4; ++ct) {
            const unsigned nib = (unsigned)(mrow >> ((ct << 4) + (quad << 2))) & 0xFu;
            float p0 = (nib & 1u) ? __builtin_amdgcn_exp2f(sc[ct][0]) : 0.f;
            float p1 = (nib & 2u) ? __builtin_amdgcn_exp2f(sc[ct][1]) : 0.f;
            float p2 = (nib & 4u) ? __builtin_amdgcn_exp2f(sc[ct][2]) : 0.f;
            float p3 = (nib & 8u) ? __builtin_amdgcn_exp2f(sc[ct][3]) : 0.f;
            l_acc += (p0 + p1) + (p2 + p3);
            const int col = (ct << 4) + (quad << 2);
            *(unsigned int*)&Pb[prow][col]     = pack_bf2(p0, p1);
            *(unsigned int*)&Pb[prow][col + 2] = pack_bf2(p2, p3);
        }
        // No barrier: wave w reads back only its own rows (lgkmcnt-ordered)

        sh8 pf[2];
        #pragma unroll
        for (int kc2 = 0; kc2 < 2; ++kc2)
            pf[kc2] = *(const sh8*)&Pb[prow][(kc2 << 5) + (quad << 3)];

        // PV: O[16 q][96 hd] += P[16][64] @ V[64][96]
        #pragma unroll
        for (int t = 0; t < 6; ++t)
            #pragma unroll
            for (int kc2 = 0; kc2 < 2; ++kc2) {
                const sh8 vf = *(const sh8*)&Vs[(t << 4) + nl][(kc2 << 5) + (quad << 3)];
                o[t] = __builtin_amdgcn_mfma_f32_16x16x32_bf16(pf[kc2], vf, o[t], 0, 0, 0);
            }
        __syncthreads();   // (b) all reads done; drains K/V/mask prefetch
    }

    // Row sums: lane (quad,nl) has partial over its 16 kv; combine quads.
    l_acc += __shfl_xor(l_acc, 16);
    l_acc += __shfl_xor(l_acc, 32);
    const float inv = 1.0f / l_acc;   // full sum for q = w*16+nl, all quads

    // Epilogue: O/l + residual. O rows are q = w*16 + quad*4 + r; fetch the
    // matching inv from lane (quad*4+r) (lanes 0..15 hold q=w*16+nl).
    #pragma unroll
    for (int r = 0; r < 4; ++r) {
        const float invr = __shfl(inv, (quad << 2) + r);
        const int srow = sq0 + (w << 4) + (quad << 2) + r;
        const size_t base = ((size_t)b * NS + srow) * ND + h * NHD;
        #pragma unroll
        for (int t = 0; t < 6; ++t) {
            const int d = (t << 4) + nl;
            out[base + d] = o[t][r] * invr + features[base + d];
        }
    }
}

// ---------------------------------------------------------------------------
// Kernel 3: in-place LayerNorm over last dim (768). One wave per row.
// ---------------------------------------------------------------------------
__global__ __launch_bounds__(256) void ln_kernel(
    float* __restrict__ out, const float* __restrict__ gamma,
    const float* __restrict__ beta)
{
    const int row = (blockIdx.x << 2) + (threadIdx.x >> 6);
    const int lane = threadIdx.x & 63;
    float* p = out + (size_t)row * ND;

    float4 v[3];
    float s = 0.f, sq = 0.f;
    #pragma unroll
    for (int i = 0; i < 3; ++i) {
        v[i] = *(const float4*)&p[(i << 8) + (lane << 2)];
        s += v[i].x + v[i].y + v[i].z + v[i].w;
        sq += v[i].x * v[i].x + v[i].y * v[i].y + v[i].z * v[i].z + v[i].w * v[i].w;
    }
    #pragma unroll
    for (int off = 32; off; off >>= 1) {
        s += __shfl_xor(s, off);
        sq += __shfl_xor(sq, off);
    }
    const float mu = s * (1.0f / ND);
    const float var = sq * (1.0f / ND) - mu * mu;
    const float rs = rsqrtf(var + 1e-5f);
    #pragma unroll
    for (int i = 0; i < 3; ++i) {
        const int d = (i << 8) + (lane << 2);
        const float4 g = *(const float4*)&gamma[d];
        const float4 be = *(const float4*)&beta[d];
        float4 ov;
        ov.x = (v[i].x - mu) * rs * g.x + be.x;
        ov.y = (v[i].y - mu) * rs * g.y + be.y;
        ov.z = (v[i].z - mu) * rs * g.z + be.z;
        ov.w = (v[i].w - mu) * rs * g.w + be.w;
        *(float4*)&p[d] = ov;
    }
}

// ---------------------------------------------------------------------------
extern "C" void kernel_launch(void* const* d_in, const int* in_sizes, int n_in,
                              void* d_out, int out_size, void* d_ws, size_t ws_size,
                              hipStream_t stream) {
    (void)in_sizes; (void)n_in; (void)out_size;

    const float* features = (const float*)d_in[0];
    const int*   adj      = (const int*)d_in[1];
    const float* Wq       = (const float*)d_in[2];
    const float* bq       = (const float*)d_in[3];
    const float* Wk       = (const float*)d_in[4];
    const float* bk       = (const float*)d_in[5];
    const float* Wv       = (const float*)d_in[6];
    const float* bv       = (const float*)d_in[7];
    const float* gamma    = (const float*)d_in[8];
    const float* beta     = (const float*)d_in[9];
    float* out = (float*)d_out;

    // bf16 X and W live in d_out (fully overwritten later by attn+ln).
    __hip_bfloat16* Xb = (__hip_bfloat16*)d_out;
    __hip_bfloat16* Wb = Xb + (size_t)NX;
    // Q/K/V bf16 in workspace (V stored transposed [B,H,HD,S]).
    __hip_bfloat16* Qb = (__hip_bfloat16*)d_ws;
    __hip_bfloat16* Kb = Qb + (size_t)NX;
    __hip_bfloat16* Vb = Kb + (size_t)NX;
    // Packed adj mask after Vb -- only if the workspace is big enough.
    unsigned long long* Mask = (unsigned long long*)(Vb + (size_t)NX);
    const size_t ws_need = (size_t)NX * 2 * 3 + NMASK64 * 8;
    const bool use_mask = (ws_size >= ws_need);

    // 0) fp32 -> bf16 convert (X + 3 weights)
    cvt_bf16<<<(NX + 3 * NW) / (8 * 256), 256, 0, stream>>>(
        features, Wq, Wk, Wv, Xb, Wb);

    // 0b) adj -> bitmask (128 MB -> 4 MB), only when ws has room
    if (use_mask)
        adj_mask<<<2048, 256, 0, stream>>>(adj, Mask);

    // 1) QKV projections: grid (N/128, M/128, 3)
    dim3 g1(ND / 128, (NB * NS) / 128, 3);
    qkv_mfma<<<g1, 256, 0, stream>>>(Xb, Wb, bq, bk, bv, Qb, Kb, Vb);

    // 2) MFMA flash attention + residual: grid (S/64, H, B)
    dim3 g2(NS / 64, NH, NB);
    if (use_mask)
        attn_mfma<1><<<g2, 256, 0, stream>>>(Qb, Kb, Vb, adj, Mask, features, out);
    else
        attn_mfma<0><<<g2, 256, 0, stream>>>(Qb, Kb, Vb, adj, Mask, features, out);

    // 3) LayerNorm in place
    ln_kernel<<<(NB * NS) / 4, 256, 0, stream>>>(out, gamma, beta);
}

// Round 3
// 582.078 us; speedup vs baseline: 1.2749x; 1.1492x over previous
//
#include <hip/hip_runtime.h>
#include <hip/hip_bf16.h>

// Problem constants
#define NB 8
#define NS 2048
#define ND 768
#define NH 8
#define NHD 96
#define ATTN_SCALE 0.1020620726159658f   // 1/sqrt(96)
#define LOG2E 1.4426950408889634f
#define QSCALE (ATTN_SCALE * LOG2E)      // folded into Q so probs = exp2(s)

#define NX (NB * NS * ND)                // 12,582,912 feature elems
#define NW (ND * ND)                     // 589,824 per weight
#define NMASK64 ((size_t)NB * NS * NS / 64)  // 524,288 ulongs = 4 MB

typedef short sh8 __attribute__((ext_vector_type(8)));   // 8 bf16 = 4 VGPRs (MFMA A/B frag)
typedef float f4  __attribute__((ext_vector_type(4)));   // MFMA C/D frag

__device__ __forceinline__ unsigned int pack_bf2(float a, float b) {
    __hip_bfloat162 h = __float22bfloat162_rn(make_float2(a, b));
    return *reinterpret_cast<unsigned int*>(&h);
}

__device__ __forceinline__ void async16(const void* g, void* l) {
    __builtin_amdgcn_global_load_lds(
        (const __attribute__((address_space(1))) unsigned int*)g,
        (__attribute__((address_space(3))) unsigned int*)l, 16, 0, 0);
}

// ---------------------------------------------------------------------------
// Kernel 0: convert X (fp32) and Wq/Wk/Wv (fp32) to bf16.
// ---------------------------------------------------------------------------
__global__ __launch_bounds__(256) void cvt_bf16(
    const float* __restrict__ X, const float* __restrict__ Wq,
    const float* __restrict__ Wk, const float* __restrict__ Wv,
    __hip_bfloat16* __restrict__ Xb, __hip_bfloat16* __restrict__ Wb)
{
    const long long i8 = ((long long)blockIdx.x * 256 + threadIdx.x) * 8;
    const float* src; __hip_bfloat16* dst; long long off;
    if (i8 < NX) { src = X; dst = Xb; off = i8; }
    else {
        const long long j = i8 - NX;
        const int w = (int)(j / NW);
        off = j - (long long)w * NW;
        src = (w == 0) ? Wq : (w == 1) ? Wk : Wv;
        dst = Wb + (long long)w * NW;
    }
    const float4 a = *(const float4*)&src[off];
    const float4 b = *(const float4*)&src[off + 4];
    const uint4 o = make_uint4(pack_bf2(a.x, a.y), pack_bf2(a.z, a.w),
                               pack_bf2(b.x, b.y), pack_bf2(b.z, b.w));
    *(uint4*)&dst[off] = o;
}

// ---------------------------------------------------------------------------
// Kernel 0b: bit-pack adj (int32 0/1, 128 MB) into 64-bit column masks (4 MB).
// ---------------------------------------------------------------------------
__global__ __launch_bounds__(256) void adj_mask(
    const int* __restrict__ adj, unsigned long long* __restrict__ mask)
{
    const int wid  = (blockIdx.x << 2) + (threadIdx.x >> 6);
    const int lane = threadIdx.x & 63;
    const int nwaves = 2048 * 4;
    for (size_t u = wid; u < NMASK64; u += nwaves) {
        const int v = adj[u * 64 + lane];
        const unsigned long long m = __ballot(v != 0);
        if (lane == 0) mask[u] = m;
    }
}

// ---------------------------------------------------------------------------
// Kernel 1: QKV projection (m97-style 128x128 tile, BK=64, async staging).
// ---------------------------------------------------------------------------
__global__ __launch_bounds__(256) void qkv_mfma(
    const __hip_bfloat16* __restrict__ Xb, const __hip_bfloat16* __restrict__ Wb,
    const float* __restrict__ bq, const float* __restrict__ bk,
    const float* __restrict__ bv,
    __hip_bfloat16* __restrict__ Qo, __hip_bfloat16* __restrict__ Ko,
    __hip_bfloat16* __restrict__ Vo)
{
    __shared__ unsigned short As[128 * 64];  // X tile [m][k] flat (async dest)
    __shared__ unsigned short Bs[128 * 64];  // W tile [n][k] flat

    const int z = blockIdx.z;
    const __hip_bfloat16* W = Wb + (size_t)z * NW;
    const float* bias = (z == 0) ? bq : (z == 1) ? bk : bv;

    const int tid  = threadIdx.x;
    const int w    = tid >> 6;
    const int lane = tid & 63;
    const int quad = lane >> 4;
    const int nl   = lane & 15;
    const int wm = w >> 1, wn = w & 1;
    const int m0 = blockIdx.y << 7;
    const int n0 = blockIdx.x << 7;

    const bool swapped = (z != 2);

    const f4 zero4 = {0.f, 0.f, 0.f, 0.f};
    f4 acc[4][4];
    #pragma unroll
    for (int i = 0; i < 4; ++i)
        #pragma unroll
        for (int j = 0; j < 4; ++j) acc[i][j] = zero4;

    for (int k0 = 0; k0 < ND; k0 += 64) {
        #pragma unroll
        for (int i = 0; i < 4; ++i) {
            const int cb = (i << 8) + (w << 6);      // wave-uniform chunk base
            const int c  = cb + lane;
            const int row = c >> 3, col = (c & 7) << 3;
            async16(&Xb[(size_t)(m0 + row) * ND + k0 + col], &As[(size_t)cb << 3]);
            async16(&W [(size_t)(n0 + row) * ND + k0 + col], &Bs[(size_t)cb << 3]);
        }
        __syncthreads();   // drains vmcnt -> staging visible

        const unsigned short* Arow = swapped ? Bs : As;
        const unsigned short* Brow = swapped ? As : Bs;
        sh8 af[4][2], bfr[4][2];
        #pragma unroll
        for (int t = 0; t < 4; ++t)
            #pragma unroll
            for (int kc = 0; kc < 2; ++kc) {
                af[t][kc]  = *(const sh8*)&Arow[((wm << 6) + (t << 4) + nl) * 64 + (kc << 5) + (quad << 3)];
                bfr[t][kc] = *(const sh8*)&Brow[((wn << 6) + (t << 4) + nl) * 64 + (kc << 5) + (quad << 3)];
            }
        #pragma unroll
        for (int mt = 0; mt < 4; ++mt)
            #pragma unroll
            for (int nt = 0; nt < 4; ++nt)
                #pragma unroll
                for (int kc = 0; kc < 2; ++kc)
                    acc[mt][nt] = __builtin_amdgcn_mfma_f32_16x16x32_bf16(
                        af[mt][kc], bfr[nt][kc], acc[mt][nt], 0, 0, 0);
        __syncthreads();
    }

    if (swapped) {
        __hip_bfloat16* Out = (z == 0) ? Qo : Ko;
        const float sc = (z == 0) ? QSCALE : 1.0f;
        #pragma unroll
        for (int mt = 0; mt < 4; ++mt) {
            const int nb = n0 + (wm << 6) + (mt << 4) + (quad << 2);  // 4-aligned
            const int hh = nb / NHD, hd0 = nb % NHD;
            const float4 bn = *(const float4*)&bias[nb];
            #pragma unroll
            for (int nt = 0; nt < 4; ++nt) {
                const int m = m0 + (wn << 6) + (nt << 4) + nl;
                const int bb = m >> 11;
                const int s  = m & (NS - 1);
                const f4 a = acc[mt][nt];
                const uint2 pk = make_uint2(
                    pack_bf2((a[0] + bn.x) * sc, (a[1] + bn.y) * sc),
                    pack_bf2((a[2] + bn.z) * sc, (a[3] + bn.w) * sc));
                *(uint2*)&Out[((size_t)(bb * NH + hh) * NS + s) * NHD + hd0] = pk;
            }
        }
    } else {
        #pragma unroll
        for (int mt = 0; mt < 4; ++mt) {
            const int mb = m0 + (wm << 6) + (mt << 4) + (quad << 2);
            const int bb = mb >> 11;
            const int s0 = mb & (NS - 1);
            #pragma unroll
            for (int nt = 0; nt < 4; ++nt) {
                const int n = n0 + (wn << 6) + (nt << 4) + nl;
                const int hh = n / NHD, hd = n % NHD;
                const float bn = bias[n];
                const f4 a = acc[mt][nt];
                const uint2 pk = make_uint2(pack_bf2(a[0] + bn, a[1] + bn),
                                            pack_bf2(a[2] + bn, a[3] + bn));
                *(uint2*)&Vo[((size_t)(bb * NH + hh) * NHD + hd) * NS + s0] = pk;
            }
        }
    }
}

// ---------------------------------------------------------------------------
// Kernel 2: MFMA flash attention + residual.
// Round-3 restructure (LDS-bandwidth-driven):
//  (1) QBLK=128: each wave owns 32 q rows (qn=2 subtiles of 16). K/V LDS
//      reads per wave per tile are invariant, so doubling q-rows per wave
//      halves LDS bytes per FLOP (8.1 -> 4.6 GB total). K/V frags loaded
//      once, reused for both qn MFMAs.
//  (2) LDS 59 KB -> exactly 2 blocks/CU -> 512 slots, grid 1024 = 2.0
//      tail-free generations (3-block configs give 1.33 gens = 33% tail).
//  (3) Vs/Pb row stride 72 -> 80 shorts (160 B): b128 same-bank-start
//      clusters drop 8 -> 4 lanes.
//  (4) Barrier (b) is a raw s_barrier with lgkmcnt(0)-only drain: K/V/mask
//      prefetch stays in flight across it; the single vmcnt(0) per iter is
//      at (a), a full iteration after issue.
// ---------------------------------------------------------------------------
template<int USEM>
__global__ __launch_bounds__(256)
__attribute__((amdgpu_waves_per_eu(2, 2)))
void attn_mfma(
    const __hip_bfloat16* __restrict__ Qg, const __hip_bfloat16* __restrict__ Kg,
    const __hip_bfloat16* __restrict__ Vtg, const int* __restrict__ adj,
    const unsigned long long* __restrict__ amask,
    const float* __restrict__ features, float* __restrict__ out)
{
    __shared__ unsigned short Ks[2][64][96];  // unpadded async16 image, dbuf, swizzled
    __shared__ unsigned short Vs[96][80];     // [d][kv], padded (160B rows)
    __shared__ unsigned short Pb[128][80];    // P bf16 [q][kv], padded (160B rows)

    const int tid  = threadIdx.x;
    const int w    = tid >> 6;
    const int lane = tid & 63;
    const int quad = lane >> 4;
    const int nl   = lane & 15;

    // XCD-aware remap over 1024 blocks: XCD k = batch k, qt fastest.
    const int flat = blockIdx.x + (blockIdx.y << 4) + (blockIdx.z << 7);
    const int wid  = ((flat & 7) << 7) + (flat >> 3);
    const int qt = wid & 15, h = (wid >> 4) & 7, b = wid >> 7;
    const int sq0 = qt << 7;

    const size_t bh = (size_t)b * NH + h;
    const __hip_bfloat16* Qbase = Qg + (bh * NS + sq0) * NHD;
    const __hip_bfloat16* Kbase = Kg + bh * NS * NHD;   // [s][hd], tile-linear
    const __hip_bfloat16* Vbase = Vtg + bh * NHD * NS;  // V^T: [hd][s]
    // Per-lane q rows: q0 = sq0 + w*32 + nl, q1 = q0 + 16.
    const int* adjr0 = adj + ((size_t)b * NS + sq0 + (w << 5) + nl) * NS;
    const unsigned long long* mrowp =
        amask + ((size_t)b * NS + sq0 + (w << 5) + nl) * (NS / 64);
    // qn=1 mask row offset: 16 rows * (NS/64=32) = 512 u64s.

    // V staging coords (loop-invariant): 768 chunks = 96 rows x 8
    int vrow[3], vc8[3];
    #pragma unroll
    for (int i = 0; i < 3; ++i) {
        const int f = tid + (i << 8);
        vrow[i] = f >> 3; vc8[i] = f & 7;
    }

    // K source-chunk swizzle (loop-invariant)
    int ksrc[3];
    #pragma unroll
    for (int i = 0; i < 3; ++i) {
        const int c  = (i << 8) + tid;
        const int kr = c / 12, kcc = c - kr * 12;
        ksrc[i] = kr * 12 + (kcc ^ ((kr >> 1) & 3));
    }
    const int kswz = ((nl >> 1) & 3) << 3;   // read-side XOR, ushort units

    // Q fragments (B-operand), 2 q-subtiles, pre-scaled by QSCALE
    sh8 qf[2][3];
    #pragma unroll
    for (int qn = 0; qn < 2; ++qn)
        #pragma unroll
        for (int kc = 0; kc < 3; ++kc)
            qf[qn][kc] = *(const sh8*)&Qbase[(size_t)((w << 5) + (qn << 4) + nl) * NHD
                                             + kc * 32 + (quad << 3)];

    const f4 zero4 = {0.f, 0.f, 0.f, 0.f};
    f4 o[2][6];
    #pragma unroll
    for (int qn = 0; qn < 2; ++qn)
        #pragma unroll
        for (int t = 0; t < 6; ++t) o[qn][t] = zero4;
    float l_acc0 = 0.f, l_acc1 = 0.f;

    // Preloop: async K(0) -> Ks[0]; V(0) -> regs; mask(0) -> regs.
    #pragma unroll
    for (int i = 0; i < 3; ++i) {
        const int cb = (i << 8) + (w << 6);
        async16(&Kbase[(size_t)ksrc[i] << 3], &Ks[0][0][(size_t)cb << 3]);
    }
    uint4 vr[3];
    #pragma unroll
    for (int i = 0; i < 3; ++i)
        vr[i] = *(const uint4*)&Vbase[(size_t)vrow[i] * NS + (vc8[i] << 3)];
    unsigned long long mcur0 = 0, mcur1 = 0, mnx0 = 0, mnx1 = 0;
    if constexpr (USEM) { mcur0 = mrowp[0]; mcur1 = mrowp[512]; }

    for (int kt = 0; kt < 32; ++kt) {
        const int sk0 = kt << 6;
        const int buf = kt & 1;

        // Commit prefetched V regs to LDS
        #pragma unroll
        for (int i = 0; i < 3; ++i)
            *(uint4*)&Vs[vrow[i]][vc8[i] << 3] = vr[i];
        __syncthreads();   // (a): vmcnt(0)+lgkmcnt(0) -> K async + commits visible

        unsigned long long mrow0, mrow1;
        if constexpr (USEM) {
            mrow0 = mcur0; mrow1 = mcur1;     // pipelined one iter ahead
        } else {
            mrow0 = 0; mrow1 = 0;
            for (int j = 0; j < 64; ++j) {
                mrow0 |= (unsigned long long)(adjr0[sk0 + j] != 0) << j;
                mrow1 |= (unsigned long long)(adjr0[(size_t)16 * NS + sk0 + j] != 0) << j;
            }
        }

        if (kt < 31) {
            const int skn = sk0 + 64;
            // V(kt+1) -> regs
            #pragma unroll
            for (int i = 0; i < 3; ++i)
                vr[i] = *(const uint4*)&Vbase[(size_t)vrow[i] * NS + skn + (vc8[i] << 3)];
            // K(kt+1) -> other LDS buffer, zero registers
            #pragma unroll
            for (int i = 0; i < 3; ++i) {
                const int cb = (i << 8) + (w << 6);
                async16(&Kbase[((size_t)skn * 12 + ksrc[i]) << 3],
                        &Ks[buf ^ 1][0][(size_t)cb << 3]);
            }
            if constexpr (USEM) { mnx0 = mrowp[kt + 1]; mnx1 = mrowp[512 + kt + 1]; }
        }

        // Scores, swapped: sc[ct][qn] = K_tile(ct) x Q(qn) -> C[kv][q].
        // K frag loaded once, reused for both qn.
        f4 sc[4][2];
        #pragma unroll
        for (int ct = 0; ct < 4; ++ct) { sc[ct][0] = zero4; sc[ct][1] = zero4; }
        #pragma unroll
        for (int ct = 0; ct < 4; ++ct)
            #pragma unroll
            for (int kc = 0; kc < 3; ++kc) {
                const sh8 kf = *(const sh8*)&Ks[buf][(ct << 4) + nl]
                                               [(kc * 32 + (quad << 3)) ^ kswz];
                sc[ct][0] = __builtin_amdgcn_mfma_f32_16x16x32_bf16(kf, qf[0][kc], sc[ct][0], 0, 0, 0);
                sc[ct][1] = __builtin_amdgcn_mfma_f32_16x16x32_bf16(kf, qf[1][kc], sc[ct][1], 0, 0, 0);
            }

        // Softmax numerators: p = maskbit ? 2^s : 0; write packed b64 to Pb.
        const int prow = (w << 5) + nl;
        #pragma unroll
        for (int ct = 0; ct < 4; ++ct) {
            #pragma unroll
            for (int qn = 0; qn < 2; ++qn) {
                const unsigned long long mrow = qn ? mrow1 : mrow0;
                const unsigned nib = (unsigned)(mrow >> ((ct << 4) + (quad << 2))) & 0xFu;
                const f4 s = sc[ct][qn];
                const float p0 = (nib & 1u) ? __builtin_amdgcn_exp2f(s[0]) : 0.f;
                const float p1 = (nib & 2u) ? __builtin_amdgcn_exp2f(s[1]) : 0.f;
                const float p2 = (nib & 4u) ? __builtin_amdgcn_exp2f(s[2]) : 0.f;
                const float p3 = (nib & 8u) ? __builtin_amdgcn_exp2f(s[3]) : 0.f;
                if (qn) l_acc1 += (p0 + p1) + (p2 + p3);
                else    l_acc0 += (p0 + p1) + (p2 + p3);
                *(uint2*)&Pb[prow + (qn << 4)][(ct << 4) + (quad << 2)] =
                    make_uint2(pack_bf2(p0, p1), pack_bf2(p2, p3));
            }
        }
        // No barrier: wave reads back only its own 32 rows (lgkmcnt-ordered)

        sh8 pf[2][2];
        #pragma unroll
        for (int qn = 0; qn < 2; ++qn)
            #pragma unroll
            for (int kc2 = 0; kc2 < 2; ++kc2)
                pf[qn][kc2] = *(const sh8*)&Pb[prow + (qn << 4)][(kc2 << 5) + (quad << 3)];

        // PV: O[32 q][96 hd] += P[32][64] @ V[64][96]; V frag reused for both qn
        #pragma unroll
        for (int t = 0; t < 6; ++t)
            #pragma unroll
            for (int kc2 = 0; kc2 < 2; ++kc2) {
                const sh8 vf = *(const sh8*)&Vs[(t << 4) + nl][(kc2 << 5) + (quad << 3)];
                o[0][t] = __builtin_amdgcn_mfma_f32_16x16x32_bf16(pf[0][kc2], vf, o[0][t], 0, 0, 0);
                o[1][t] = __builtin_amdgcn_mfma_f32_16x16x32_bf16(pf[1][kc2], vf, o[1][t], 0, 0, 0);
            }

        // (b): raw barrier -- LDS reads retired, prefetches stay in flight.
        asm volatile("s_waitcnt lgkmcnt(0)" ::: "memory");
        __builtin_amdgcn_s_barrier();
        __builtin_amdgcn_sched_barrier(0);

        mcur0 = mnx0; mcur1 = mnx1;
    }

    // Row sums: lane holds partial over its quad's 16 kv; combine quads.
    l_acc0 += __shfl_xor(l_acc0, 16);
    l_acc0 += __shfl_xor(l_acc0, 32);
    l_acc1 += __shfl_xor(l_acc1, 16);
    l_acc1 += __shfl_xor(l_acc1, 32);
    const float inv0 = 1.0f / l_acc0;
    const float inv1 = 1.0f / l_acc1;

    // Epilogue: O/l + residual. O rows: q = w*32 + qn*16 + quad*4 + r.
    #pragma unroll
    for (int qn = 0; qn < 2; ++qn) {
        #pragma unroll
        for (int r = 0; r < 4; ++r) {
            const float invr = __shfl(qn ? inv1 : inv0, (quad << 2) + r);
            const int srow = sq0 + (w << 5) + (qn << 4) + (quad << 2) + r;
            const size_t base = ((size_t)b * NS + srow) * ND + h * NHD;
            #pragma unroll
            for (int t = 0; t < 6; ++t) {
                const int d = (t << 4) + nl;
                out[base + d] = o[qn][t][r] * invr + features[base + d];
            }
        }
    }
}

// ---------------------------------------------------------------------------
// Kernel 3: in-place LayerNorm over last dim (768). One wave per row.
// ---------------------------------------------------------------------------
__global__ __launch_bounds__(256) void ln_kernel(
    float* __restrict__ out, const float* __restrict__ gamma,
    const float* __restrict__ beta)
{
    const int row = (blockIdx.x << 2) + (threadIdx.x >> 6);
    const int lane = threadIdx.x & 63;
    float* p = out + (size_t)row * ND;

    float4 v[3];
    float s = 0.f, sq = 0.f;
    #pragma unroll
    for (int i = 0; i < 3; ++i) {
        v[i] = *(const float4*)&p[(i << 8) + (lane << 2)];
        s += v[i].x + v[i].y + v[i].z + v[i].w;
        sq += v[i].x * v[i].x + v[i].y * v[i].y + v[i].z * v[i].z + v[i].w * v[i].w;
    }
    #pragma unroll
    for (int off = 32; off; off >>= 1) {
        s += __shfl_xor(s, off);
        sq += __shfl_xor(sq, off);
    }
    const float mu = s * (1.0f / ND);
    const float var = sq * (1.0f / ND) - mu * mu;
    const float rs = rsqrtf(var + 1e-5f);
    #pragma unroll
    for (int i = 0; i < 3; ++i) {
        const int d = (i << 8) + (lane << 2);
        const float4 g = *(const float4*)&gamma[d];
        const float4 be = *(const float4*)&beta[d];
        float4 ov;
        ov.x = (v[i].x - mu) * rs * g.x + be.x;
        ov.y = (v[i].y - mu) * rs * g.y + be.y;
        ov.z = (v[i].z - mu) * rs * g.z + be.z;
        ov.w = (v[i].w - mu) * rs * g.w + be.w;
        *(float4*)&p[d] = ov;
    }
}

// ---------------------------------------------------------------------------
extern "C" void kernel_launch(void* const* d_in, const int* in_sizes, int n_in,
                              void* d_out, int out_size, void* d_ws, size_t ws_size,
                              hipStream_t stream) {
    (void)in_sizes; (void)n_in; (void)out_size;

    const float* features = (const float*)d_in[0];
    const int*   adj      = (const int*)d_in[1];
    const float* Wq       = (const float*)d_in[2];
    const float* bq       = (const float*)d_in[3];
    const float* Wk       = (const float*)d_in[4];
    const float* bk       = (const float*)d_in[5];
    const float* Wv       = (const float*)d_in[6];
    const float* bv       = (const float*)d_in[7];
    const float* gamma    = (const float*)d_in[8];
    const float* beta     = (const float*)d_in[9];
    float* out = (float*)d_out;

    // bf16 X and W live in d_out (fully overwritten later by attn+ln).
    __hip_bfloat16* Xb = (__hip_bfloat16*)d_out;
    __hip_bfloat16* Wb = Xb + (size_t)NX;
    // Q/K/V bf16 in workspace (V stored transposed [B,H,HD,S]).
    __hip_bfloat16* Qb = (__hip_bfloat16*)d_ws;
    __hip_bfloat16* Kb = Qb + (size_t)NX;
    __hip_bfloat16* Vb = Kb + (size_t)NX;
    // Packed adj mask after Vb -- only if the workspace is big enough.
    unsigned long long* Mask = (unsigned long long*)(Vb + (size_t)NX);
    const size_t ws_need = (size_t)NX * 2 * 3 + NMASK64 * 8;
    const bool use_mask = (ws_size >= ws_need);

    // 0) fp32 -> bf16 convert (X + 3 weights)
    cvt_bf16<<<(NX + 3 * NW) / (8 * 256), 256, 0, stream>>>(
        features, Wq, Wk, Wv, Xb, Wb);

    // 0b) adj -> bitmask (128 MB -> 4 MB), only when ws has room
    if (use_mask)
        adj_mask<<<2048, 256, 0, stream>>>(adj, Mask);

    // 1) QKV projections: grid (N/128, M/128, 3)
    dim3 g1(ND / 128, (NB * NS) / 128, 3);
    qkv_mfma<<<g1, 256, 0, stream>>>(Xb, Wb, bq, bk, bv, Qb, Kb, Vb);

    // 2) MFMA flash attention + residual: grid (S/128, H, B) = 1024 blocks
    dim3 g2(NS / 128, NH, NB);
    if (use_mask)
        attn_mfma<1><<<g2, 256, 0, stream>>>(Qb, Kb, Vb, adj, Mask, features, out);
    else
        attn_mfma<0><<<g2, 256, 0, stream>>>(Qb, Kb, Vb, adj, Mask, features, out);

    // 3) LayerNorm in place
    ln_kernel<<<(NB * NS) / 4, 256, 0, stream>>>(out, gamma, beta);
}

// Round 4
// 544.504 us; speedup vs baseline: 1.3629x; 1.0690x over previous
//
#include <hip/hip_runtime.h>
#include <hip/hip_bf16.h>

// Problem constants
#define NB 8
#define NS 2048
#define ND 768
#define NH 8
#define NHD 96
#define ATTN_SCALE 0.1020620726159658f   // 1/sqrt(96)
#define LOG2E 1.4426950408889634f
#define QSCALE (ATTN_SCALE * LOG2E)      // folded into Q so probs = exp2(s)

#define NX (NB * NS * ND)                // 12,582,912 feature elems
#define NW (ND * ND)                     // 589,824 per weight
#define NMASK64 ((size_t)NB * NS * NS / 64)  // 524,288 ulongs = 4 MB

typedef short sh8 __attribute__((ext_vector_type(8)));   // 8 bf16 = 4 VGPRs (MFMA A/B frag)
typedef float f4  __attribute__((ext_vector_type(4)));   // MFMA C/D frag

__device__ __forceinline__ unsigned int pack_bf2(float a, float b) {
    __hip_bfloat162 h = __float22bfloat162_rn(make_float2(a, b));
    return *reinterpret_cast<unsigned int*>(&h);
}

__device__ __forceinline__ void async16(const void* g, void* l) {
    __builtin_amdgcn_global_load_lds(
        (const __attribute__((address_space(1))) unsigned int*)g,
        (__attribute__((address_space(3))) unsigned int*)l, 16, 0, 0);
}

// ---------------------------------------------------------------------------
// Kernel 0: convert X (fp32) and Wq/Wk/Wv (fp32) to bf16.
// ---------------------------------------------------------------------------
__global__ __launch_bounds__(256) void cvt_bf16(
    const float* __restrict__ X, const float* __restrict__ Wq,
    const float* __restrict__ Wk, const float* __restrict__ Wv,
    __hip_bfloat16* __restrict__ Xb, __hip_bfloat16* __restrict__ Wb)
{
    const long long i8 = ((long long)blockIdx.x * 256 + threadIdx.x) * 8;
    const float* src; __hip_bfloat16* dst; long long off;
    if (i8 < NX) { src = X; dst = Xb; off = i8; }
    else {
        const long long j = i8 - NX;
        const int w = (int)(j / NW);
        off = j - (long long)w * NW;
        src = (w == 0) ? Wq : (w == 1) ? Wk : Wv;
        dst = Wb + (long long)w * NW;
    }
    const float4 a = *(const float4*)&src[off];
    const float4 b = *(const float4*)&src[off + 4];
    const uint4 o = make_uint4(pack_bf2(a.x, a.y), pack_bf2(a.z, a.w),
                               pack_bf2(b.x, b.y), pack_bf2(b.z, b.w));
    *(uint4*)&dst[off] = o;
}

// ---------------------------------------------------------------------------
// Kernel 0b: bit-pack adj (int32 0/1, 128 MB) into 64-bit column masks (4 MB).
// ---------------------------------------------------------------------------
__global__ __launch_bounds__(256) void adj_mask(
    const int* __restrict__ adj, unsigned long long* __restrict__ mask)
{
    const int wid  = (blockIdx.x << 2) + (threadIdx.x >> 6);
    const int lane = threadIdx.x & 63;
    const int nwaves = 2048 * 4;
    for (size_t u = wid; u < NMASK64; u += nwaves) {
        const int v = adj[u * 64 + lane];
        const unsigned long long m = __ballot(v != 0);
        if (lane == 0) mask[u] = m;
    }
}

// ---------------------------------------------------------------------------
// Kernel 1: QKV projection (m97-style 128x128 tile, BK=64, async staging).
// ---------------------------------------------------------------------------
__global__ __launch_bounds__(256) void qkv_mfma(
    const __hip_bfloat16* __restrict__ Xb, const __hip_bfloat16* __restrict__ Wb,
    const float* __restrict__ bq, const float* __restrict__ bk,
    const float* __restrict__ bv,
    __hip_bfloat16* __restrict__ Qo, __hip_bfloat16* __restrict__ Ko,
    __hip_bfloat16* __restrict__ Vo)
{
    __shared__ unsigned short As[128 * 64];  // X tile [m][k] flat (async dest)
    __shared__ unsigned short Bs[128 * 64];  // W tile [n][k] flat

    const int z = blockIdx.z;
    const __hip_bfloat16* W = Wb + (size_t)z * NW;
    const float* bias = (z == 0) ? bq : (z == 1) ? bk : bv;

    const int tid  = threadIdx.x;
    const int w    = tid >> 6;
    const int lane = tid & 63;
    const int quad = lane >> 4;
    const int nl   = lane & 15;
    const int wm = w >> 1, wn = w & 1;
    const int m0 = blockIdx.y << 7;
    const int n0 = blockIdx.x << 7;

    const bool swapped = (z != 2);

    const f4 zero4 = {0.f, 0.f, 0.f, 0.f};
    f4 acc[4][4];
    #pragma unroll
    for (int i = 0; i < 4; ++i)
        #pragma unroll
        for (int j = 0; j < 4; ++j) acc[i][j] = zero4;

    for (int k0 = 0; k0 < ND; k0 += 64) {
        #pragma unroll
        for (int i = 0; i < 4; ++i) {
            const int cb = (i << 8) + (w << 6);      // wave-uniform chunk base
            const int c  = cb + lane;
            const int row = c >> 3, col = (c & 7) << 3;
            async16(&Xb[(size_t)(m0 + row) * ND + k0 + col], &As[(size_t)cb << 3]);
            async16(&W [(size_t)(n0 + row) * ND + k0 + col], &Bs[(size_t)cb << 3]);
        }
        __syncthreads();   // drains vmcnt -> staging visible

        const unsigned short* Arow = swapped ? Bs : As;
        const unsigned short* Brow = swapped ? As : Bs;
        sh8 af[4][2], bfr[4][2];
        #pragma unroll
        for (int t = 0; t < 4; ++t)
            #pragma unroll
            for (int kc = 0; kc < 2; ++kc) {
                af[t][kc]  = *(const sh8*)&Arow[((wm << 6) + (t << 4) + nl) * 64 + (kc << 5) + (quad << 3)];
                bfr[t][kc] = *(const sh8*)&Brow[((wn << 6) + (t << 4) + nl) * 64 + (kc << 5) + (quad << 3)];
            }
        #pragma unroll
        for (int mt = 0; mt < 4; ++mt)
            #pragma unroll
            for (int nt = 0; nt < 4; ++nt)
                #pragma unroll
                for (int kc = 0; kc < 2; ++kc)
                    acc[mt][nt] = __builtin_amdgcn_mfma_f32_16x16x32_bf16(
                        af[mt][kc], bfr[nt][kc], acc[mt][nt], 0, 0, 0);
        __syncthreads();
    }

    if (swapped) {
        __hip_bfloat16* Out = (z == 0) ? Qo : Ko;
        const float sc = (z == 0) ? QSCALE : 1.0f;
        #pragma unroll
        for (int mt = 0; mt < 4; ++mt) {
            const int nb = n0 + (wm << 6) + (mt << 4) + (quad << 2);  // 4-aligned
            const int hh = nb / NHD, hd0 = nb % NHD;
            const float4 bn = *(const float4*)&bias[nb];
            #pragma unroll
            for (int nt = 0; nt < 4; ++nt) {
                const int m = m0 + (wn << 6) + (nt << 4) + nl;
                const int bb = m >> 11;
                const int s  = m & (NS - 1);
                const f4 a = acc[mt][nt];
                const uint2 pk = make_uint2(
                    pack_bf2((a[0] + bn.x) * sc, (a[1] + bn.y) * sc),
                    pack_bf2((a[2] + bn.z) * sc, (a[3] + bn.w) * sc));
                *(uint2*)&Out[((size_t)(bb * NH + hh) * NS + s) * NHD + hd0] = pk;
            }
        }
    } else {
        #pragma unroll
        for (int mt = 0; mt < 4; ++mt) {
            const int mb = m0 + (wm << 6) + (mt << 4) + (quad << 2);
            const int bb = mb >> 11;
            const int s0 = mb & (NS - 1);
            #pragma unroll
            for (int nt = 0; nt < 4; ++nt) {
                const int n = n0 + (wn << 6) + (nt << 4) + nl;
                const int hh = n / NHD, hd = n % NHD;
                const float bn = bias[n];
                const f4 a = acc[mt][nt];
                const uint2 pk = make_uint2(pack_bf2(a[0] + bn, a[1] + bn),
                                            pack_bf2(a[2] + bn, a[3] + bn));
                *(uint2*)&Vo[((size_t)(bb * NH + hh) * NHD + hd) * NS + s0] = pk;
            }
        }
    }
}

// ---------------------------------------------------------------------------
// Kernel 2: MFMA flash attention + residual.
// Round-4 restructure (occupancy-driven; r3 counters: Occ 20.6%, MfmaUtil 19%,
// nothing saturated -> 2 waves/SIMD can't hide latency):
//  (1) KVBLK 64 -> 32 (QBLK stays 128): LDS bytes/FLOP unchanged, LDS size
//      26.6 KB -> 4 blocks/CU = 16 waves/CU, and grid 1024 = EXACTLY one
//      generation (no tail). waves_per_eu(4) caps regs at 128 (natural ~96).
//  (2) Vs/Pb: reg-staged, so unpadded [.][32] rows + XOR chunk swizzle
//      (chunk ^= row&3) -> b128 reads hit the 8-access/bank floor exactly.
//  (3) Masks become u32/tile (pipelined); K keeps async16 + source swizzle.
//  (4) T5 setprio(1) around the MFMA+softmax cluster (role-diverse waves at
//      4 blocks/CU; m191 +4-7%).
//  Canary: WRITE_SIZE must stay ~49 MB; growth = spill from the 128-reg cap.
// ---------------------------------------------------------------------------
#define VCOL(row, ch) ((((ch) ^ ((row) & 3)) << 3))

template<int USEM>
__global__ __launch_bounds__(256)
__attribute__((amdgpu_waves_per_eu(4)))
void attn_mfma(
    const __hip_bfloat16* __restrict__ Qg, const __hip_bfloat16* __restrict__ Kg,
    const __hip_bfloat16* __restrict__ Vtg, const int* __restrict__ adj,
    const unsigned long long* __restrict__ amask,
    const float* __restrict__ features, float* __restrict__ out)
{
    __shared__ unsigned short Ks[2][32][96];  // async16 image, dbuf, src-swizzled
    __shared__ unsigned short Vs[96][32];     // [d][kv], XOR chunk swizzle
    __shared__ unsigned short Pb[128][32];    // P bf16 [q][kv], XOR chunk swizzle

    const int tid  = threadIdx.x;
    const int w    = tid >> 6;
    const int lane = tid & 63;
    const int quad = lane >> 4;
    const int nl   = lane & 15;

    // XCD-aware remap over 1024 blocks: XCD k = batch k, qt fastest.
    const int flat = blockIdx.x + (blockIdx.y << 4) + (blockIdx.z << 7);
    const int wid  = ((flat & 7) << 7) + (flat >> 3);
    const int qt = wid & 15, h = (wid >> 4) & 7, b = wid >> 7;
    const int sq0 = qt << 7;

    const size_t bh = (size_t)b * NH + h;
    const __hip_bfloat16* Qbase = Qg + (bh * NS + sq0) * NHD;
    const __hip_bfloat16* Kbase = Kg + bh * NS * NHD;   // [s][hd], tile-linear
    const __hip_bfloat16* Vbase = Vtg + bh * NHD * NS;  // V^T: [hd][s]
    // Per-lane q rows: q0 = sq0 + w*32 + nl, q1 = q0 + 16.
    const int* adjr0 = adj + ((size_t)b * NS + sq0 + (w << 5) + nl) * NS;
    // u32 view of the mask: row stride NS/32 = 64 u32; element kt covers 32 kv.
    const unsigned int* mrow32 =
        (const unsigned int*)amask + ((size_t)b * NS + sq0 + (w << 5) + nl) * (NS / 32);
    // qn=1 row offset: 16 rows * 64 = 1024 u32.

    // V staging: tile = 96 rows x 32 shorts = 384 uint4 chunks; round 0 = tid,
    // round 1 = 256+tid (tid<128 only; wave-uniform guard).
    const bool half = (tid < 128);
    const int vrow0 = tid >> 2,        vcc0 = tid & 3;
    const int vrow1 = 64 + (tid >> 2), vcc1 = tid & 3;

    // K source-chunk swizzle (12 chunks per 96-short row)
    int ksrc0, ksrc1;
    {
        const int c0 = tid;       const int kr0 = c0 / 12;
        ksrc0 = kr0 * 12 + ((c0 - kr0 * 12) ^ ((kr0 >> 1) & 3));
        const int c1 = 256 + tid; const int kr1 = c1 / 12;
        ksrc1 = kr1 * 12 + ((c1 - kr1 * 12) ^ ((kr1 >> 1) & 3));
    }
    const int kswz = ((nl >> 1) & 3) << 3;   // read-side XOR, shorts

    // Q fragments (B-operand), 2 q-subtiles, pre-scaled by QSCALE
    sh8 qf[2][3];
    #pragma unroll
    for (int qn = 0; qn < 2; ++qn)
        #pragma unroll
        for (int kc = 0; kc < 3; ++kc)
            qf[qn][kc] = *(const sh8*)&Qbase[(size_t)((w << 5) + (qn << 4) + nl) * NHD
                                             + kc * 32 + (quad << 3)];

    const f4 zero4 = {0.f, 0.f, 0.f, 0.f};
    f4 o[2][6];
    #pragma unroll
    for (int qn = 0; qn < 2; ++qn)
        #pragma unroll
        for (int t = 0; t < 6; ++t) o[qn][t] = zero4;
    float l_acc0 = 0.f, l_acc1 = 0.f;

    // Preloop: async K(0) -> Ks[0]; V(0) -> regs; mask(0) -> regs.
    async16(&Kbase[(size_t)ksrc0 << 3], &Ks[0][0][(size_t)(w << 6) << 3]);
    if (half)
        async16(&Kbase[(size_t)ksrc1 << 3], &Ks[0][0][(size_t)(256 + (w << 6)) << 3]);
    uint4 vr0, vr1;
    vr0 = *(const uint4*)&Vbase[(size_t)vrow0 * NS + (vcc0 << 3)];
    if (half) vr1 = *(const uint4*)&Vbase[(size_t)vrow1 * NS + (vcc1 << 3)];
    unsigned int mcur0 = 0, mcur1 = 0, mnx0 = 0, mnx1 = 0;
    if constexpr (USEM) { mcur0 = mrow32[0]; mcur1 = mrow32[1024]; }

    for (int kt = 0; kt < 64; ++kt) {
        const int sk0 = kt << 5;
        const int buf = kt & 1;

        // Commit prefetched V regs to LDS (XOR chunk swizzle)
        *(uint4*)&Vs[vrow0][VCOL(vrow0, vcc0)] = vr0;
        if (half) *(uint4*)&Vs[vrow1][VCOL(vrow1, vcc1)] = vr1;
        __syncthreads();   // (a): vmcnt(0)+lgkmcnt(0) -> K async + commits visible

        unsigned int mrow0, mrow1;
        if constexpr (USEM) {
            mrow0 = mcur0; mrow1 = mcur1;     // pipelined one iter ahead
        } else {
            mrow0 = 0; mrow1 = 0;
            for (int j = 0; j < 32; ++j) {
                mrow0 |= (unsigned int)(adjr0[sk0 + j] != 0) << j;
                mrow1 |= (unsigned int)(adjr0[(size_t)16 * NS + sk0 + j] != 0) << j;
            }
        }

        if (kt < 63) {
            const int skn = sk0 + 32;
            // V(kt+1) -> regs
            vr0 = *(const uint4*)&Vbase[(size_t)vrow0 * NS + skn + (vcc0 << 3)];
            if (half) vr1 = *(const uint4*)&Vbase[(size_t)vrow1 * NS + skn + (vcc1 << 3)];
            // K(kt+1) -> other LDS buffer, zero registers
            async16(&Kbase[((size_t)skn * 12 + ksrc0) << 3],
                    &Ks[buf ^ 1][0][(size_t)(w << 6) << 3]);
            if (half)
                async16(&Kbase[((size_t)skn * 12 + ksrc1) << 3],
                        &Ks[buf ^ 1][0][(size_t)(256 + (w << 6)) << 3]);
            if constexpr (USEM) { mnx0 = mrow32[kt + 1]; mnx1 = mrow32[1024 + kt + 1]; }
        }

        __builtin_amdgcn_s_setprio(1);

        // Scores, swapped: sc[ct][qn] = K_tile(ct) x Q(qn) -> C[kv][q].
        f4 sc[2][2];
        #pragma unroll
        for (int ct = 0; ct < 2; ++ct) { sc[ct][0] = zero4; sc[ct][1] = zero4; }
        #pragma unroll
        for (int ct = 0; ct < 2; ++ct)
            #pragma unroll
            for (int kc = 0; kc < 3; ++kc) {
                const sh8 kf = *(const sh8*)&Ks[buf][(ct << 4) + nl]
                                               [(kc * 32 + (quad << 3)) ^ kswz];
                sc[ct][0] = __builtin_amdgcn_mfma_f32_16x16x32_bf16(kf, qf[0][kc], sc[ct][0], 0, 0, 0);
                sc[ct][1] = __builtin_amdgcn_mfma_f32_16x16x32_bf16(kf, qf[1][kc], sc[ct][1], 0, 0, 0);
            }

        // Softmax numerators: p = maskbit ? 2^s : 0; packed b64 writes to Pb.
        const int prow = (w << 5) + nl;
        #pragma unroll
        for (int ct = 0; ct < 2; ++ct) {
            #pragma unroll
            for (int qn = 0; qn < 2; ++qn) {
                const unsigned int mrow = qn ? mrow1 : mrow0;
                const unsigned nib = (mrow >> ((ct << 4) + (quad << 2))) & 0xFu;
                const f4 s = sc[ct][qn];
                const float p0 = (nib & 1u) ? __builtin_amdgcn_exp2f(s[0]) : 0.f;
                const float p1 = (nib & 2u) ? __builtin_amdgcn_exp2f(s[1]) : 0.f;
                const float p2 = (nib & 4u) ? __builtin_amdgcn_exp2f(s[2]) : 0.f;
                const float p3 = (nib & 8u) ? __builtin_amdgcn_exp2f(s[3]) : 0.f;
                if (qn) l_acc1 += (p0 + p1) + (p2 + p3);
                else    l_acc0 += (p0 + p1) + (p2 + p3);
                const int row = prow + (qn << 4);
                const int col = VCOL(row, (ct << 1) + (quad >> 1)) + ((quad & 1) << 2);
                *(uint2*)&Pb[row][col] = make_uint2(pack_bf2(p0, p1), pack_bf2(p2, p3));
            }
        }
        // No barrier: wave reads back only its own 32 rows (in-order LDS)

        sh8 pf[2];
        #pragma unroll
        for (int qn = 0; qn < 2; ++qn) {
            const int row = prow + (qn << 4);
            pf[qn] = *(const sh8*)&Pb[row][VCOL(row, quad)];
        }

        // PV: O[32 q][96 hd] += P[32][32] @ V[32][96]; V frag reused across qn
        #pragma unroll
        for (int t = 0; t < 6; ++t) {
            const int vrw = (t << 4) + nl;
            const sh8 vf = *(const sh8*)&Vs[vrw][VCOL(vrw, quad)];
            o[0][t] = __builtin_amdgcn_mfma_f32_16x16x32_bf16(pf[0], vf, o[0][t], 0, 0, 0);
            o[1][t] = __builtin_amdgcn_mfma_f32_16x16x32_bf16(pf[1], vf, o[1][t], 0, 0, 0);
        }
        __builtin_amdgcn_s_setprio(0);

        // (b): raw barrier -- LDS reads retired, prefetches stay in flight.
        asm volatile("s_waitcnt lgkmcnt(0)" ::: "memory");
        __builtin_amdgcn_s_barrier();
        __builtin_amdgcn_sched_barrier(0);

        mcur0 = mnx0; mcur1 = mnx1;
    }

    // Row sums: lane holds partial over its quad's kv share; combine quads.
    l_acc0 += __shfl_xor(l_acc0, 16);
    l_acc0 += __shfl_xor(l_acc0, 32);
    l_acc1 += __shfl_xor(l_acc1, 16);
    l_acc1 += __shfl_xor(l_acc1, 32);
    const float inv0 = 1.0f / l_acc0;
    const float inv1 = 1.0f / l_acc1;

    // Epilogue: O/l + residual. O rows: q = w*32 + qn*16 + quad*4 + r.
    #pragma unroll
    for (int qn = 0; qn < 2; ++qn) {
        #pragma unroll
        for (int r = 0; r < 4; ++r) {
            const float invr = __shfl(qn ? inv1 : inv0, (quad << 2) + r);
            const int srow = sq0 + (w << 5) + (qn << 4) + (quad << 2) + r;
            const size_t base = ((size_t)b * NS + srow) * ND + h * NHD;
            #pragma unroll
            for (int t = 0; t < 6; ++t) {
                const int d = (t << 4) + nl;
                out[base + d] = o[qn][t][r] * invr + features[base + d];
            }
        }
    }
}

// ---------------------------------------------------------------------------
// Kernel 3: in-place LayerNorm over last dim (768). One wave per row.
// ---------------------------------------------------------------------------
__global__ __launch_bounds__(256) void ln_kernel(
    float* __restrict__ out, const float* __restrict__ gamma,
    const float* __restrict__ beta)
{
    const int row = (blockIdx.x << 2) + (threadIdx.x >> 6);
    const int lane = threadIdx.x & 63;
    float* p = out + (size_t)row * ND;

    float4 v[3];
    float s = 0.f, sq = 0.f;
    #pragma unroll
    for (int i = 0; i < 3; ++i) {
        v[i] = *(const float4*)&p[(i << 8) + (lane << 2)];
        s += v[i].x + v[i].y + v[i].z + v[i].w;
        sq += v[i].x * v[i].x + v[i].y * v[i].y + v[i].z * v[i].z + v[i].w * v[i].w;
    }
    #pragma unroll
    for (int off = 32; off; off >>= 1) {
        s += __shfl_xor(s, off);
        sq += __shfl_xor(sq, off);
    }
    const float mu = s * (1.0f / ND);
    const float var = sq * (1.0f / ND) - mu * mu;
    const float rs = rsqrtf(var + 1e-5f);
    #pragma unroll
    for (int i = 0; i < 3; ++i) {
        const int d = (i << 8) + (lane << 2);
        const float4 g = *(const float4*)&gamma[d];
        const float4 be = *(const float4*)&beta[d];
        float4 ov;
        ov.x = (v[i].x - mu) * rs * g.x + be.x;
        ov.y = (v[i].y - mu) * rs * g.y + be.y;
        ov.z = (v[i].z - mu) * rs * g.z + be.z;
        ov.w = (v[i].w - mu) * rs * g.w + be.w;
        *(float4*)&p[d] = ov;
    }
}

// ---------------------------------------------------------------------------
extern "C" void kernel_launch(void* const* d_in, const int* in_sizes, int n_in,
                              void* d_out, int out_size, void* d_ws, size_t ws_size,
                              hipStream_t stream) {
    (void)in_sizes; (void)n_in; (void)out_size;

    const float* features = (const float*)d_in[0];
    const int*   adj      = (const int*)d_in[1];
    const float* Wq       = (const float*)d_in[2];
    const float* bq       = (const float*)d_in[3];
    const float* Wk       = (const float*)d_in[4];
    const float* bk       = (const float*)d_in[5];
    const float* Wv       = (const float*)d_in[6];
    const float* bv       = (const float*)d_in[7];
    const float* gamma    = (const float*)d_in[8];
    const float* beta     = (const float*)d_in[9];
    float* out = (float*)d_out;

    // bf16 X and W live in d_out (fully overwritten later by attn+ln).
    __hip_bfloat16* Xb = (__hip_bfloat16*)d_out;
    __hip_bfloat16* Wb = Xb + (size_t)NX;
    // Q/K/V bf16 in workspace (V stored transposed [B,H,HD,S]).
    __hip_bfloat16* Qb = (__hip_bfloat16*)d_ws;
    __hip_bfloat16* Kb = Qb + (size_t)NX;
    __hip_bfloat16* Vb = Kb + (size_t)NX;
    // Packed adj mask after Vb -- only if the workspace is big enough.
    unsigned long long* Mask = (unsigned long long*)(Vb + (size_t)NX);
    const size_t ws_need = (size_t)NX * 2 * 3 + NMASK64 * 8;
    const bool use_mask = (ws_size >= ws_need);

    // 0) fp32 -> bf16 convert (X + 3 weights)
    cvt_bf16<<<(NX + 3 * NW) / (8 * 256), 256, 0, stream>>>(
        features, Wq, Wk, Wv, Xb, Wb);

    // 0b) adj -> bitmask (128 MB -> 4 MB), only when ws has room
    if (use_mask)
        adj_mask<<<2048, 256, 0, stream>>>(adj, Mask);

    // 1) QKV projections: grid (N/128, M/128, 3)
    dim3 g1(ND / 128, (NB * NS) / 128, 3);
    qkv_mfma<<<g1, 256, 0, stream>>>(Xb, Wb, bq, bk, bv, Qb, Kb, Vb);

    // 2) MFMA flash attention + residual: grid (S/128, H, B) = 1024 blocks
    dim3 g2(NS / 128, NH, NB);
    if (use_mask)
        attn_mfma<1><<<g2, 256, 0, stream>>>(Qb, Kb, Vb, adj, Mask, features, out);
    else
        attn_mfma<0><<<g2, 256, 0, stream>>>(Qb, Kb, Vb, adj, Mask, features, out);

    // 3) LayerNorm in place
    ln_kernel<<<(NB * NS) / 4, 256, 0, stream>>>(out, gamma, beta);
}